// Round 2
// baseline (1720.927 us; speedup 1.0000x reference)
//
#include <hip/hip_runtime.h>

// ---------------------------------------------------------------------------
// 2-layer GCN (unnormalized sum aggregation + self loops), fp32.
//   h1   = x @ W1^T + b1                      [N,128]
//   agg1 = h1 + segment_sum(h1[row] -> col)   (self loop == init with h1)
//   h2   = relu(agg1) @ W2^T + b2             [N,64]
//   out  = h2 + segment_sum(h2[row] -> col)
//   out  = log_softmax(out, axis=1)
// edge_index arrives as int32 (harness: integer -> const int*).
// ---------------------------------------------------------------------------

#define K_DIM 128  // inner dim of both GEMMs

// Tiled fp32 GEMM: H[M,F] = act(X[M,128]) @ W[F,128]^T + b
// LDS tiles are XOR-swizzled on the float4 index (q ^= row&7) so the k-loop
// column reads are broadcast / conflict-free while keeping 16B alignment.
// DUAL_OUT additionally writes H2 (the aggregation init == self-loop term).
template <int F, bool RELU_IN, bool DUAL_OUT>
__global__ __launch_bounds__(256) void gemm_kernel(
    const float* __restrict__ X, const float* __restrict__ W,
    const float* __restrict__ bias, float* __restrict__ H,
    float* __restrict__ H2, int M) {
  constexpr int K  = K_DIM;
  constexpr int CT = F / 4;        // threads along cols (32 for F=128, 16 for F=64)
  constexpr int RG = 256 / CT;     // row groups per block
  constexpr int TM = RG * 4;       // rows per block (32 or 64)

  __shared__ float xs[TM][K];
  __shared__ float ws[F][K];

  const int tid = threadIdx.x;
  const int m0  = blockIdx.x * TM;

  // ---- stage W[F,128] into LDS, swizzled ----
  {
    constexpr int TOT4 = F * (K / 4);
    for (int f = tid; f < TOT4; f += 256) {
      const int c = f / (K / 4);
      const int q = f % (K / 4);
      float4 v = reinterpret_cast<const float4*>(W)[f];
      const int qs = q ^ (c & 7);
      *reinterpret_cast<float4*>(&ws[c][qs * 4]) = v;
    }
  }
  // ---- stage X tile into LDS (optional ReLU on read), swizzled ----
  {
    constexpr int TOT4 = TM * (K / 4);
    for (int f = tid; f < TOT4; f += 256) {
      const int r = f / (K / 4);
      const int q = f % (K / 4);
      const int m = m0 + r;
      float4 v = make_float4(0.f, 0.f, 0.f, 0.f);
      if (m < M) {
        v = reinterpret_cast<const float4*>(X)[m * (K / 4) + q];
        if (RELU_IN) {
          v.x = fmaxf(v.x, 0.f); v.y = fmaxf(v.y, 0.f);
          v.z = fmaxf(v.z, 0.f); v.w = fmaxf(v.w, 0.f);
        }
      }
      const int qs = q ^ (r & 7);
      *reinterpret_cast<float4*>(&xs[r][qs * 4]) = v;
    }
  }
  __syncthreads();

  const int tc = tid % CT;
  const int tr = tid / CT;
  const int c0 = tc * 4;
  const int r0 = tr * 4;

  float acc[4][4] = {};

#pragma unroll 4
  for (int q = 0; q < K / 4; ++q) {
    float4 a[4], w[4];
#pragma unroll
    for (int i = 0; i < 4; ++i)
      a[i] = *reinterpret_cast<const float4*>(&xs[r0 + i][(q ^ ((r0 + i) & 7)) * 4]);
#pragma unroll
    for (int j = 0; j < 4; ++j)
      w[j] = *reinterpret_cast<const float4*>(&ws[c0 + j][(q ^ ((c0 + j) & 7)) * 4]);
#pragma unroll
    for (int i = 0; i < 4; ++i)
#pragma unroll
      for (int j = 0; j < 4; ++j)
        acc[i][j] += a[i].x * w[j].x + a[i].y * w[j].y +
                     a[i].z * w[j].z + a[i].w * w[j].w;
  }

  const float4 bv = *reinterpret_cast<const float4*>(&bias[c0]);
#pragma unroll
  for (int i = 0; i < 4; ++i) {
    const int m = m0 + r0 + i;
    if (m < M) {
      float4 o;
      o.x = acc[i][0] + bv.x;
      o.y = acc[i][1] + bv.y;
      o.z = acc[i][2] + bv.z;
      o.w = acc[i][3] + bv.w;
      *reinterpret_cast<float4*>(&H[(size_t)m * F + c0]) = o;
      if (DUAL_OUT)
        *reinterpret_cast<float4*>(&H2[(size_t)m * F + c0]) = o;
    }
  }
}

// Edge scatter: AGG[col[e]] += H[row[e]]  (float4 gather, 4 scalar atomics)
template <int F>
__global__ __launch_bounds__(256) void scatter_kernel(
    const int* __restrict__ rows, const int* __restrict__ cols,
    const float* __restrict__ H, float* __restrict__ AGG, int E) {
  constexpr int TPE = F / 4;       // threads per edge
  constexpr int EPB = 256 / TPE;   // edges per block
  const int e = blockIdx.x * EPB + threadIdx.x / TPE;
  if (e >= E) return;
  const int chunk = threadIdx.x % TPE;
  const int r = rows[e];
  const int c = cols[e];
  const float4 v = reinterpret_cast<const float4*>(H)[(size_t)r * TPE + chunk];
  float* dst = &AGG[(size_t)c * F + chunk * 4];
  atomicAdd(dst + 0, v.x);
  atomicAdd(dst + 1, v.y);
  atomicAdd(dst + 2, v.z);
  atomicAdd(dst + 3, v.w);
}

// In-place log_softmax over 64 cols: one wave (64 lanes) per row.
__global__ __launch_bounds__(256) void logsoftmax_kernel(float* __restrict__ OUT,
                                                         int M) {
  const int wave = (int)((blockIdx.x * 256 + threadIdx.x) >> 6);
  const int lane = threadIdx.x & 63;
  if (wave >= M) return;
  const size_t idx = (size_t)wave * 64 + lane;
  const float v = OUT[idx];
  float m = v;
#pragma unroll
  for (int s = 32; s > 0; s >>= 1) m = fmaxf(m, __shfl_xor(m, s));
  const float ex = __expf(v - m);
  float sum = ex;
#pragma unroll
  for (int s = 32; s > 0; s >>= 1) sum += __shfl_xor(sum, s);
  OUT[idx] = v - m - __logf(sum);
}

extern "C" void kernel_launch(void* const* d_in, const int* in_sizes, int n_in,
                              void* d_out, int out_size, void* d_ws,
                              size_t ws_size, hipStream_t stream) {
  const float* x  = (const float*)d_in[0];
  const int* ei   = (const int*)d_in[1];   // edge_index as int32, [2,E] row-major
  const float* W1 = (const float*)d_in[2];
  const float* b1 = (const float*)d_in[3];
  const float* W2 = (const float*)d_in[4];
  const float* b2 = (const float*)d_in[5];
  float* out = (float*)d_out;

  const int N = in_sizes[0] / 128;
  const int E = in_sizes[1] / 2;
  const int* rows = ei;      // edge_index[0] (source)
  const int* cols = ei + E;  // edge_index[1] (destination)

  float* h1   = (float*)d_ws;               // N*128
  float* agg1 = h1 + (size_t)N * 128;       // N*128
  float* h2   = h1;                         // reuse: h1 dead after scatter1

  // Layer 1: projection (+ self-loop init of agg1), then edge scatter-add.
  gemm_kernel<128, false, true>
      <<<(N + 31) / 32, 256, 0, stream>>>(x, W1, b1, h1, agg1, N);
  scatter_kernel<128>
      <<<(E + 7) / 8, 256, 0, stream>>>(rows, cols, h1, agg1, E);

  // Layer 2: relu on input, projection (+ self-loop init of d_out), scatter.
  gemm_kernel<64, true, true>
      <<<(N + 63) / 64, 256, 0, stream>>>(agg1, W2, b2, h2, out, N);
  scatter_kernel<64>
      <<<(E + 15) / 16, 256, 0, stream>>>(rows, cols, h2, out, E);

  // log_softmax over the 64 logits, in place on d_out.
  logsoftmax_kernel<<<(N + 3) / 4, 256, 0, stream>>>(out, N);
}

// Round 3
// 410.742 us; speedup vs baseline: 4.1898x; 4.1898x over previous
//
#include <hip/hip_runtime.h>

// ---------------------------------------------------------------------------
// 2-layer GCN (unnormalized sum aggregation + self loops), fp32.
//   h1   = x @ W1^T + b1                      [N,128]
//   agg1 = h1 + segment_sum(h1[row] -> col)   (gather via on-device CSR)
//   h2   = relu(agg1) @ W2^T + b2             [N,64]
//   out  = log_softmax(h2 + segment_sum(h2[row] -> col), axis=1)
//
// Round 2 -> 3: replaced 115M fp32 atomicAdds (1.6 ms, 4x write-amplified)
// with CSR build (int atomics) + deterministic per-node wave gather.
// ---------------------------------------------------------------------------

#define K_DIM 128

// ---------------- GEMM: H[M,F] = act(X[M,128]) @ W[F,128]^T + b ------------
template <int F, bool RELU_IN>
__global__ __launch_bounds__(256) void gemm_kernel(
    const float* __restrict__ X, const float* __restrict__ W,
    const float* __restrict__ bias, float* __restrict__ H, int M) {
  constexpr int K  = K_DIM;
  constexpr int CT = F / 4;        // threads along cols
  constexpr int RG = 256 / CT;     // row groups per block
  constexpr int TM = RG * 4;       // rows per block

  __shared__ float xs[TM][K];
  __shared__ float ws[F][K];

  const int tid = threadIdx.x;
  const int m0  = blockIdx.x * TM;

  {  // stage W, swizzled on the float4 index (conflict-free k-loop reads)
    constexpr int TOT4 = F * (K / 4);
    for (int f = tid; f < TOT4; f += 256) {
      const int c = f / (K / 4);
      const int q = f % (K / 4);
      float4 v = reinterpret_cast<const float4*>(W)[f];
      const int qs = q ^ (c & 7);
      *reinterpret_cast<float4*>(&ws[c][qs * 4]) = v;
    }
  }
  {  // stage X tile (optional ReLU), swizzled
    constexpr int TOT4 = TM * (K / 4);
    for (int f = tid; f < TOT4; f += 256) {
      const int r = f / (K / 4);
      const int q = f % (K / 4);
      const int m = m0 + r;
      float4 v = make_float4(0.f, 0.f, 0.f, 0.f);
      if (m < M) {
        v = reinterpret_cast<const float4*>(X)[m * (K / 4) + q];
        if (RELU_IN) {
          v.x = fmaxf(v.x, 0.f); v.y = fmaxf(v.y, 0.f);
          v.z = fmaxf(v.z, 0.f); v.w = fmaxf(v.w, 0.f);
        }
      }
      const int qs = q ^ (r & 7);
      *reinterpret_cast<float4*>(&xs[r][qs * 4]) = v;
    }
  }
  __syncthreads();

  const int tc = tid % CT;
  const int tr = tid / CT;
  const int c0 = tc * 4;
  const int r0 = tr * 4;

  float acc[4][4] = {};

#pragma unroll 4
  for (int q = 0; q < K / 4; ++q) {
    float4 a[4], w[4];
#pragma unroll
    for (int i = 0; i < 4; ++i)
      a[i] = *reinterpret_cast<const float4*>(&xs[r0 + i][(q ^ ((r0 + i) & 7)) * 4]);
#pragma unroll
    for (int j = 0; j < 4; ++j)
      w[j] = *reinterpret_cast<const float4*>(&ws[c0 + j][(q ^ ((c0 + j) & 7)) * 4]);
#pragma unroll
    for (int i = 0; i < 4; ++i)
#pragma unroll
      for (int j = 0; j < 4; ++j)
        acc[i][j] += a[i].x * w[j].x + a[i].y * w[j].y +
                     a[i].z * w[j].z + a[i].w * w[j].w;
  }

  const float4 bv = *reinterpret_cast<const float4*>(&bias[c0]);
#pragma unroll
  for (int i = 0; i < 4; ++i) {
    const int m = m0 + r0 + i;
    if (m < M) {
      float4 o;
      o.x = acc[i][0] + bv.x;
      o.y = acc[i][1] + bv.y;
      o.z = acc[i][2] + bv.z;
      o.w = acc[i][3] + bv.w;
      *reinterpret_cast<float4*>(&H[(size_t)m * F + c0]) = o;
    }
  }
}

// ---------------- CSR build ------------------------------------------------
__global__ __launch_bounds__(256) void zero_kernel(int* __restrict__ p, int n) {
  const int i = blockIdx.x * 256 + threadIdx.x;
  if (i < n) p[i] = 0;
}

__global__ __launch_bounds__(256) void hist_kernel(const int* __restrict__ cols,
                                                   int* __restrict__ deg, int E) {
  const int e = blockIdx.x * 256 + threadIdx.x;
  if (e < E) atomicAdd(&deg[cols[e]], 1);
}

// Single-block exclusive scan of deg[N] -> offs[N+1].
__global__ __launch_bounds__(1024) void scan_kernel(const int* __restrict__ deg,
                                                    int* __restrict__ offs, int N) {
  __shared__ int sums[1024];
  const int t = threadIdx.x;
  const int chunk = (N + 1023) / 1024;
  const int lo = t * chunk;
  const int hi = min(lo + chunk, N);
  int s = 0;
  for (int i = lo; i < hi; ++i) s += deg[i];
  sums[t] = s;
  __syncthreads();
  for (int d = 1; d < 1024; d <<= 1) {
    const int v = (t >= d) ? sums[t - d] : 0;
    __syncthreads();
    sums[t] += v;
    __syncthreads();
  }
  int excl = (t == 0) ? 0 : sums[t - 1];
  for (int i = lo; i < hi; ++i) {
    offs[i] = excl;
    excl += deg[i];
  }
  if (lo < N && hi == N) offs[N] = excl;
}

__global__ __launch_bounds__(256) void fill_kernel(
    const int* __restrict__ rows, const int* __restrict__ cols,
    const int* __restrict__ offs, int* __restrict__ cursor,
    int* __restrict__ srcs, int E) {
  const int e = blockIdx.x * 256 + threadIdx.x;
  if (e >= E) return;
  const int c = cols[e];
  const int pos = atomicAdd(&cursor[c], 1);
  srcs[offs[c] + pos] = rows[e];
}

// ---------------- Gather aggregation (one wave per node) -------------------
// F=128: each lane owns a float2 slice. acc init = self-loop term.
__global__ __launch_bounds__(256) void gather128_kernel(
    const int* __restrict__ offs, const int* __restrict__ srcs,
    const float* __restrict__ H, float* __restrict__ AGG, int N) {
  const int node = (int)((blockIdx.x * 256 + threadIdx.x) >> 6);
  const int lane = threadIdx.x & 63;
  if (node >= N) return;
  const int beg = offs[node], end = offs[node + 1];
  float2 acc = *reinterpret_cast<const float2*>(&H[(size_t)node * 128 + lane * 2]);
  int j = beg;
  for (; j + 1 < end; j += 2) {  // unroll-by-2: two independent row loads
    const int s0 = srcs[j], s1 = srcs[j + 1];
    const float2 v0 = *reinterpret_cast<const float2*>(&H[(size_t)s0 * 128 + lane * 2]);
    const float2 v1 = *reinterpret_cast<const float2*>(&H[(size_t)s1 * 128 + lane * 2]);
    acc.x += v0.x + v1.x;
    acc.y += v0.y + v1.y;
  }
  if (j < end) {
    const int s = srcs[j];
    const float2 v = *reinterpret_cast<const float2*>(&H[(size_t)s * 128 + lane * 2]);
    acc.x += v.x;
    acc.y += v.y;
  }
  *reinterpret_cast<float2*>(&AGG[(size_t)node * 128 + lane * 2]) = acc;
}

// F=64: each lane owns one float; fused log_softmax (wave holds full row).
__global__ __launch_bounds__(256) void gather64_lsm_kernel(
    const int* __restrict__ offs, const int* __restrict__ srcs,
    const float* __restrict__ H, float* __restrict__ OUT, int N) {
  const int node = (int)((blockIdx.x * 256 + threadIdx.x) >> 6);
  const int lane = threadIdx.x & 63;
  if (node >= N) return;
  const int beg = offs[node], end = offs[node + 1];
  float acc = H[(size_t)node * 64 + lane];
  int j = beg;
  for (; j + 1 < end; j += 2) {
    const int s0 = srcs[j], s1 = srcs[j + 1];
    acc += H[(size_t)s0 * 64 + lane] + H[(size_t)s1 * 64 + lane];
  }
  if (j < end) acc += H[(size_t)srcs[j] * 64 + lane];

  float m = acc;
#pragma unroll
  for (int s = 32; s > 0; s >>= 1) m = fmaxf(m, __shfl_xor(m, s));
  float sum = __expf(acc - m);
#pragma unroll
  for (int s = 32; s > 0; s >>= 1) sum += __shfl_xor(sum, s);
  OUT[(size_t)node * 64 + lane] = acc - m - __logf(sum);
}

// ---------------------------------------------------------------------------
extern "C" void kernel_launch(void* const* d_in, const int* in_sizes, int n_in,
                              void* d_out, int out_size, void* d_ws,
                              size_t ws_size, hipStream_t stream) {
  const float* x  = (const float*)d_in[0];
  const int* ei   = (const int*)d_in[1];   // edge_index int32, [2,E] row-major
  const float* W1 = (const float*)d_in[2];
  const float* b1 = (const float*)d_in[3];
  const float* W2 = (const float*)d_in[4];
  const float* b2 = (const float*)d_in[5];
  float* out = (float*)d_out;

  const int N = in_sizes[0] / 128;
  const int E = in_sizes[1] / 2;
  const int* rows = ei;      // sources
  const int* cols = ei + E;  // destinations

  // Workspace layout (54.2 MB for N=50k, E=600k):
  float* h1   = (float*)d_ws;               // N*128 f32
  float* agg1 = h1 + (size_t)N * 128;       // N*128 f32
  float* h2   = h1;                         // reuse: h1 dead after gather1
  int* deg    = (int*)(agg1 + (size_t)N * 128);  // N
  int* cursor = deg + N;                         // N
  int* offs   = cursor + N;                      // N+1
  int* srcs   = offs + N + 1;                    // E

  const int eb = (E + 255) / 256;
  const int gb = (N * 64 + 255) / 256;  // gather: one wave per node

  // CSR build (pattern shared by both layers).
  zero_kernel<<<(2 * N + 255) / 256, 256, 0, stream>>>(deg, 2 * N);
  hist_kernel<<<eb, 256, 0, stream>>>(cols, deg, E);
  scan_kernel<<<1, 1024, 0, stream>>>(deg, offs, N);
  fill_kernel<<<eb, 256, 0, stream>>>(rows, cols, offs, cursor, srcs, E);

  // Layer 1: project, then gather (self-loop = init from h1).
  gemm_kernel<128, false>
      <<<(N + 31) / 32, 256, 0, stream>>>(x, W1, b1, h1, N);
  gather128_kernel<<<gb, 256, 0, stream>>>(offs, srcs, h1, agg1, N);

  // Layer 2: relu+project, then gather fused with log_softmax.
  gemm_kernel<64, true>
      <<<(N + 63) / 64, 256, 0, stream>>>(agg1, W2, b2, h2, N);
  gather64_lsm_kernel<<<gb, 256, 0, stream>>>(offs, srcs, h2, out, N);
}